// Round 6
// baseline (1395.108 us; speedup 1.0000x reference)
//
#include <hip/hip_runtime.h>
#include <math.h>

// Sinkhorn loss, n=m=8192, K=32, eps=1, L=10 iterations.
// Round 6: occupancy push. Grid 2048 WGs (64 row-blocks x 32 col-slices),
// wave = 32 rows, __launch_bounds__(256,8) -> target 8 blocks/CU = 8 waves/SIMD
// (round 5 ran 4). psums stored TRANSPOSED (psumT[row*32+slice]) so the bias
// finalize prologue reads 32 contiguous floats per column (8x float4).
//   z = l2e*2*x.y via bf16 hi/lo split (3 MFMAs), x pre-scaled by 2*log2e.
//   pass:  psumT[i*32+slice] = sum_{j in slice} exp2(z_ij) * pb_j
//   pb_j  = (1/n) / sum_k psumT[j*32+k]   (multiplicative bias, reciprocal)
//   loss:  sum_ij fma(z,-ln2,xsq+ysq) * exp2(z) * pa_i * pb_j
// MFMA layouts (m89/m120-verified): A elem j = A[m=lane&15][k=(lane>>4)*8+j];
// C/D: col=lane&15, row=(lane>>4)*4+reg.

#define KDIM 32
#define NPS 32                    // psum slices (grid.y)
#define LOG2E 1.44269504088896340736f
#define LN2 0.69314718055994530942f

typedef short short8 __attribute__((ext_vector_type(8)));
typedef float f32x4 __attribute__((ext_vector_type(4)));

__device__ __forceinline__ unsigned short f2bf(float f) {
    unsigned int u = __float_as_uint(f);
    u += 0x7FFF + ((u >> 16) & 1);
    return (unsigned short)(u >> 16);
}
__device__ __forceinline__ float bf2f(unsigned short b) {
    return __uint_as_float(((unsigned int)b) << 16);
}

// ------------------------------------------------------------ prep: hi/lo split
// x side pre-scaled by 2*log2e; y side unscaled.
__global__ void prep_split(const float* __restrict__ x, const float* __restrict__ y,
                           int nelem,
                           unsigned short* __restrict__ xh, unsigned short* __restrict__ xl,
                           unsigned short* __restrict__ yh, unsigned short* __restrict__ yl) {
    int i4 = (blockIdx.x * 256 + threadIdx.x) * 4;
    if (i4 >= 2 * nelem) return;
    const float* src; unsigned short* dh; unsigned short* dl; int off; float sc;
    if (i4 < nelem) { src = x; dh = xh; dl = xl; off = i4; sc = 2.0f * LOG2E; }
    else            { src = y; dh = yh; dl = yl; off = i4 - nelem; sc = 1.0f; }
    float4 v = *(const float4*)(src + off);
    v.x *= sc; v.y *= sc; v.z *= sc; v.w *= sc;
    ushort4 h, l;
    h.x = f2bf(v.x); l.x = f2bf(v.x - bf2f(h.x));
    h.y = f2bf(v.y); l.y = f2bf(v.y - bf2f(h.y));
    h.z = f2bf(v.z); l.z = f2bf(v.z - bf2f(h.z));
    h.w = f2bf(v.w); l.w = f2bf(v.w - bf2f(h.w));
    *(ushort4*)(dh + off) = h;
    *(ushort4*)(dl + off) = l;
}

// ------------------------------------------------------------ prep: row sumsq
__global__ void prep_sq(const float* __restrict__ x, const float* __restrict__ y,
                        int n, float* __restrict__ xsq, float* __restrict__ ysq,
                        float* __restrict__ pb0) {
    int i = blockIdx.x * blockDim.x + threadIdx.x;
    if (i >= 2 * n) return;
    const float* src = (i < n) ? x : y;
    int r = (i < n) ? i : i - n;
    const float4* p = (const float4*)(src + (size_t)r * KDIM);
    float s = 0.f;
#pragma unroll
    for (int q = 0; q < 8; ++q) {
        float4 v = p[q];
        s += v.x * v.x + v.y * v.y + v.z * v.z + v.w * v.w;
    }
    if (i < n) xsq[r] = s;
    else { ysq[r] = s; pb0[r] = __builtin_amdgcn_exp2f(-LOG2E * s); }
}

// ------------------------------------------------------------ pass
// Wave = 32 rows; WG = 4 waves = 128 rows. grid = (n/128, NPS); slice 256 cols.
__global__ __launch_bounds__(256, 8) void sink_pass(
    const unsigned short* __restrict__ Ah, const unsigned short* __restrict__ Alo,
    const unsigned short* __restrict__ Bh, const unsigned short* __restrict__ Blo,
    const float* __restrict__ pb_direct,     // pass 0: exp-bias, else null
    const float* __restrict__ psumT_in,      // [row*NPS + slice]
    float* __restrict__ psumT_out, int n, float inv_n) {
    __shared__ float pbl[256];
    __shared__ float red[4][32][17];

    const int tid = threadIdx.x;
    const int w = tid >> 6, lane = tid & 63;
    const int mrow = lane & 15, quad = lane >> 4, koff = quad * 8;
    const int i0 = (blockIdx.x * 4 + w) * 32;
    const int jbeg = blockIdx.y * (n / NPS);   // 256 cols

    {   // prologue: multiplicative bias for this slice's 256 cols (1 col/thread)
        int j = jbeg + tid;
        float b;
        if (pb_direct) {
            b = pb_direct[j];
        } else {
            const float4* p = (const float4*)(psumT_in + (size_t)j * NPS);
            float s = 0.f;
#pragma unroll
            for (int q = 0; q < NPS / 4; ++q) {
                float4 v = p[q];
                s += v.x + v.y + v.z + v.w;
            }
            b = inv_n / s;
        }
        pbl[tid] = b;
    }

    short8 aH[2], aL[2];
#pragma unroll
    for (int t = 0; t < 2; ++t) {
        size_t rb = (size_t)(i0 + t * 16 + mrow) * KDIM + koff;
        aH[t] = *(const short8*)(Ah + rb);
        aL[t] = *(const short8*)(Alo + rb);
    }
    __syncthreads();

    float rs[8];
#pragma unroll
    for (int q = 0; q < 8; ++q) rs[q] = 0.f;

    auto ldB = [&](int jt, short8* bh, short8* bl, float* pb) {
        const int j0 = jbeg + jt * 32;
#pragma unroll
        for (int u = 0; u < 2; ++u) {
            size_t rb = (size_t)(j0 + u * 16 + mrow) * KDIM + koff;
            bh[u] = *(const short8*)(Bh + rb);
            bl[u] = *(const short8*)(Blo + rb);
            pb[u] = pbl[jt * 32 + u * 16 + mrow];
        }
    };
    auto compute = [&](short8* bh, short8* bl, float* pb) {
#pragma unroll
        for (int t = 0; t < 2; ++t)
#pragma unroll
            for (int u = 0; u < 2; ++u) {
                f32x4 z = {0.f, 0.f, 0.f, 0.f};
                z = __builtin_amdgcn_mfma_f32_16x16x32_bf16(aH[t], bh[u], z, 0, 0, 0);
                z = __builtin_amdgcn_mfma_f32_16x16x32_bf16(aH[t], bl[u], z, 0, 0, 0);
                z = __builtin_amdgcn_mfma_f32_16x16x32_bf16(aL[t], bh[u], z, 0, 0, 0);
#pragma unroll
                for (int r = 0; r < 4; ++r)
                    rs[t * 4 + r] = fmaf(__builtin_amdgcn_exp2f(z[r]), pb[u], rs[t * 4 + r]);
            }
    };

    const int JT = (n / NPS) / 32;   // 8
    short8 bh0[2], bl0[2], bh1[2], bl1[2];
    float pb0v[2], pb1v[2];
    ldB(0, bh0, bl0, pb0v);
    for (int jt = 0; jt < JT; jt += 2) {
        ldB(jt + 1, bh1, bl1, pb1v);
        compute(bh0, bl0, pb0v);
        if (jt + 2 < JT) ldB(jt + 2, bh0, bl0, pb0v);
        compute(bh1, bl1, pb1v);
    }

#pragma unroll
    for (int t = 0; t < 2; ++t)
#pragma unroll
        for (int r = 0; r < 4; ++r)
            red[w][t * 16 + quad * 4 + r][mrow] = rs[t * 4 + r];
    __syncthreads();
    if (tid < 128) {
        int w2 = tid >> 5, row = tid & 31;
        float s = 0.f;
#pragma unroll
        for (int c = 0; c < 16; ++c) s += red[w2][row][c];
        int R = blockIdx.x * 128 + w2 * 32 + row;
        psumT_out[(size_t)R * NPS + blockIdx.y] = s;
    }
}

// ------------------------------------------------------------ loss
// Same decomposition: wave = 32 rows, WG = 128 rows, slice 256 cols.
__global__ __launch_bounds__(256, 8) void sink_loss(
    const unsigned short* __restrict__ Xh, const unsigned short* __restrict__ Xl,
    const unsigned short* __restrict__ Yh, const unsigned short* __restrict__ Yl,
    const float* __restrict__ apsumT, const float* __restrict__ bpsumT,
    const float* __restrict__ xsq, const float* __restrict__ ysq,
    float* __restrict__ partials, int n, float inv_n) {
    __shared__ float pbL[256];
    __shared__ float ysl[256];
    __shared__ float pal[128];
    __shared__ float xsl[128];
    __shared__ float red[256];

    const int tid = threadIdx.x;
    const int w = tid >> 6, lane = tid & 63;
    const int mrow = lane & 15, quad = lane >> 4, koff = quad * 8;
    const int i0 = (blockIdx.x * 4 + w) * 32;
    const int jbeg = blockIdx.y * (n / NPS);

    {   // col-side bias + ysq
        int j = jbeg + tid;
        const float4* p = (const float4*)(bpsumT + (size_t)j * NPS);
        float s = 0.f;
#pragma unroll
        for (int q = 0; q < NPS / 4; ++q) {
            float4 v = p[q];
            s += v.x + v.y + v.z + v.w;
        }
        pbL[tid] = inv_n / s;
        ysl[tid] = ysq[j];
    }
    if (tid < 128) {   // row-side bias + xsq
        int i = blockIdx.x * 128 + tid;
        const float4* p = (const float4*)(apsumT + (size_t)i * NPS);
        float s = 0.f;
#pragma unroll
        for (int q = 0; q < NPS / 4; ++q) {
            float4 v = p[q];
            s += v.x + v.y + v.z + v.w;
        }
        pal[tid] = inv_n / s;
        xsl[tid] = xsq[i];
    }

    short8 aH[2], aL[2];
#pragma unroll
    for (int t = 0; t < 2; ++t) {
        size_t rb = (size_t)(i0 + t * 16 + mrow) * KDIM + koff;
        aH[t] = *(const short8*)(Xh + rb);
        aL[t] = *(const short8*)(Xl + rb);
    }
    __syncthreads();

    float pa[8], xs[8];
#pragma unroll
    for (int t = 0; t < 2; ++t)
#pragma unroll
        for (int r = 0; r < 4; ++r) {
            int rl = w * 32 + t * 16 + quad * 4 + r;
            pa[t * 4 + r] = pal[rl];
            xs[t * 4 + r] = xsl[rl];
        }

    float acc = 0.f;

    auto ldB = [&](int jt, short8* bh, short8* bl, float* pb, float* ysv) {
#pragma unroll
        for (int u = 0; u < 2; ++u) {
            int cl = jt * 32 + u * 16 + mrow;
            size_t rb = (size_t)(jbeg + cl) * KDIM + koff;
            bh[u] = *(const short8*)(Yh + rb);
            bl[u] = *(const short8*)(Yl + rb);
            pb[u] = pbL[cl];
            ysv[u] = ysl[cl];
        }
    };
    auto compute = [&](short8* bh, short8* bl, float* pb, float* ysv) {
#pragma unroll
        for (int t = 0; t < 2; ++t)
#pragma unroll
            for (int u = 0; u < 2; ++u) {
                f32x4 z = {0.f, 0.f, 0.f, 0.f};
                z = __builtin_amdgcn_mfma_f32_16x16x32_bf16(aH[t], bh[u], z, 0, 0, 0);
                z = __builtin_amdgcn_mfma_f32_16x16x32_bf16(aH[t], bl[u], z, 0, 0, 0);
                z = __builtin_amdgcn_mfma_f32_16x16x32_bf16(aL[t], bh[u], z, 0, 0, 0);
#pragma unroll
                for (int r = 0; r < 4; ++r) {
                    float dd = z[r];
                    float e = __builtin_amdgcn_exp2f(dd) * (pa[t * 4 + r] * pb[u]);
                    float cst = fmaf(dd, -LN2, xs[t * 4 + r] + ysv[u]);
                    acc = fmaf(cst, e, acc);
                }
            }
    };

    const int JT = (n / NPS) / 32;   // 8
    short8 bh0[2], bl0[2], bh1[2], bl1[2];
    float pb0v[2], pb1v[2], ys0v[2], ys1v[2];
    ldB(0, bh0, bl0, pb0v, ys0v);
    for (int jt = 0; jt < JT; jt += 2) {
        ldB(jt + 1, bh1, bl1, pb1v, ys1v);
        compute(bh0, bl0, pb0v, ys0v);
        if (jt + 2 < JT) ldB(jt + 2, bh0, bl0, pb0v, ys0v);
        compute(bh1, bl1, pb1v, ys1v);
    }

    red[tid] = acc;
    __syncthreads();
#pragma unroll
    for (int s = 128; s > 0; s >>= 1) {
        if (tid < s) red[tid] += red[tid + s];
        __syncthreads();
    }
    if (tid == 0) partials[blockIdx.y * gridDim.x + blockIdx.x] = red[0];
}

// ------------------------------------------------------------ final reduce
__global__ void sink_reduce(const float* __restrict__ p, int nb,
                            float* __restrict__ out) {
    __shared__ float red[256];
    int tid = threadIdx.x;
    float v = 0.f;
    for (int i = tid; i < nb; i += 256) v += p[i];
    red[tid] = v;
    __syncthreads();
#pragma unroll
    for (int s = 128; s > 0; s >>= 1) {
        if (tid < s) red[tid] += red[tid + s];
        __syncthreads();
    }
    if (tid == 0) out[0] = red[0];
}

// ------------------------------------------------------------ launch
extern "C" void kernel_launch(void* const* d_in, const int* in_sizes, int n_in,
                              void* d_out, int out_size, void* d_ws, size_t ws_size,
                              hipStream_t stream) {
    const float* x = (const float*)d_in[0];
    const float* y = (const float*)d_in[1];
    const int n = in_sizes[0] / KDIM;                 // 8192
    const int nelem = n * KDIM;
    const float inv_n = 1.0f / (float)n;

    float* ws = (float*)d_ws;
    float* xsq    = ws;                               //  n
    float* ysq    = ws + n;                           //  n
    float* pb0    = ws + 2 * n;                       //  n
    float* apsumT = ws + 3 * n;                       //  NPS*n
    float* bpsumT = ws + (3 + NPS) * n;               //  NPS*n
    float* part   = ws + (3 + 2 * NPS) * n;           //  2048 (pad n)
    unsigned short* us = (unsigned short*)(ws + (4 + 2 * NPS) * n);
    unsigned short* xh = us;
    unsigned short* xl = us + nelem;
    unsigned short* yh = us + 2 * nelem;
    unsigned short* yl = us + 3 * nelem;

    dim3 grid(n / 128, NPS);                          // (64, 32) = 2048 WGs

    prep_split<<<(2 * nelem / 4 + 255) / 256, 256, 0, stream>>>(x, y, nelem, xh, xl, yh, yl);
    prep_sq<<<(2 * n + 255) / 256, 256, 0, stream>>>(x, y, n, xsq, ysq, pb0);

    sink_pass<<<grid, 256, 0, stream>>>(xh, xl, yh, yl, pb0, nullptr, apsumT, n, inv_n);
    sink_pass<<<grid, 256, 0, stream>>>(yh, yl, xh, xl, nullptr, apsumT, bpsumT, n, inv_n);
    for (int t = 1; t < 10; ++t) {
        sink_pass<<<grid, 256, 0, stream>>>(xh, xl, yh, yl, nullptr, bpsumT, apsumT, n, inv_n);
        sink_pass<<<grid, 256, 0, stream>>>(yh, yl, xh, xl, nullptr, apsumT, bpsumT, n, inv_n);
    }
    sink_loss<<<grid, 256, 0, stream>>>(xh, xl, yh, yl, apsumT, bpsumT, xsq, ysq, part, n, inv_n);
    sink_reduce<<<1, 256, 0, stream>>>(part, (n / 128) * NPS, (float*)d_out);
}